// Round 2
// baseline (3880.331 us; speedup 1.0000x reference)
//
#include <hip/hip_runtime.h>

#define DD 128
#define PP 15
#define NNODES 10000
#define NEDGES 160000

typedef __attribute__((ext_vector_type(8))) short bf16x8;
typedef __attribute__((ext_vector_type(4))) float f32x4;

__device__ inline ushort f2bf(float f) {
  unsigned u = __builtin_bit_cast(unsigned, f);
  u += 0x7FFFu + ((u >> 16) & 1u);   // round-to-nearest-even
  return (ushort)(u >> 16);
}

__device__ inline f32x4 mfma16(bf16x8 a, bf16x8 b, f32x4 c) {
  return __builtin_amdgcn_mfma_f32_16x16x32_bf16(a, b, c, 0, 0, 0);
}

// Pack fp32 weight [P][K][128] into bf16 MFMA B-fragment order:
// out[p][cb][kt][lane][e] = w[p][kt*32 + (lane>>4)*8 + e][cb*16 + (lane&15)]
__global__ __launch_bounds__(256) void pack_w(const float* __restrict__ w,
                                              ushort* __restrict__ out,
                                              int K, int total) {
  int i = blockIdx.x * 256 + threadIdx.x;
  if (i >= total) return;
  int per = K * 128;
  int p = i / per, j = i % per;
  int e = j & 7;
  int lane = (j >> 3) & 63;
  int t = j >> 9;               // cb*nkt + kt
  int nkt = K >> 5;
  int kt = t % nkt, cb = t / nkt;
  int k = kt * 32 + ((lane >> 4) << 3) + e;
  int n = (cb << 4) + (lane & 15);
  out[i] = f2bf(w[(size_t)p * per + (size_t)k * 128 + n]);
}

// ---------------- CSR build: histogram + scan + scatter ----------------
__global__ __launch_bounds__(256) void hist_kernel(const int* __restrict__ dst,
                                                   int* __restrict__ cnt) {
  int i = blockIdx.x * 256 + threadIdx.x;
  if (i < NEDGES) atomicAdd(&cnt[dst[i]], 1);
}

__global__ __launch_bounds__(256) void scan_kernel(const int* __restrict__ cnt,
                                                   int* __restrict__ row_start,
                                                   int* __restrict__ cursor) {
  __shared__ int part[256];
  const int CH = (NNODES + 255) / 256;     // 40
  int t = threadIdx.x;
  int beg = t * CH, end = min(beg + CH, NNODES);
  int s = 0;
  for (int i = beg; i < end; ++i) s += cnt[i];
  part[t] = s;
  __syncthreads();
  for (int off = 1; off < 256; off <<= 1) {
    int v = (t >= off) ? part[t - off] : 0;
    __syncthreads();
    part[t] += v;
    __syncthreads();
  }
  int run = part[t] - s;     // exclusive prefix
  for (int i = beg; i < end; ++i) {
    row_start[i] = run;
    cursor[i] = run;
    run += cnt[i];
  }
  if (t == 255) row_start[NNODES] = NEDGES;
}

__global__ __launch_bounds__(256) void scatter_kernel(const int* __restrict__ dst,
                                                      int* __restrict__ cursor,
                                                      int* __restrict__ eidx) {
  int i = blockIdx.x * 256 + threadIdx.x;
  if (i < NEDGES) {
    int pos = atomicAdd(&cursor[dst[i]], 1);
    eidx[pos] = i;
  }
}

// ---------------- edge kernel: 64 edges x 128 out per block, 4 waves ----------------
// Hlds aliased onto Alds (extra barrier after GEMM1) -> 48.5 KB LDS -> 3 blocks/CU.
__global__ __launch_bounds__(256) void edge_kernel(
    const float* __restrict__ nbuf, float* __restrict__ ebuf,
    const int* __restrict__ srcI, const int* __restrict__ dstI,
    const ushort* __restrict__ w0, const float* __restrict__ b0,
    const ushort* __restrict__ w1, const float* __restrict__ b1,
    const ushort* __restrict__ w2, const float* __restrict__ b2) {
  __shared__ ushort S[64 * 384];      // cat tile (swizzled); later reused as hidden tile
  __shared__ int slds[64], dlds[64];
  ushort* Alds = S;
  ushort* Hlds = S;

  const int tid = threadIdx.x;
  const int e0 = blockIdx.x * 64;
  const int lane = tid & 63, wv = tid >> 6;
  const int l15 = lane & 15, l4 = lane >> 4;

  if (tid < 64) slds[tid] = srcI[e0 + tid];
  else if (tid < 128) dlds[tid - 64] = dstI[e0 + tid - 64];
  __syncthreads();

  // stage cat = [n[src] | n[dst] | e] as bf16 into Alds (row stride 384, swizzled)
#pragma unroll
  for (int i = 0; i < 24; ++i) {
    int c = i * 256 + tid;
    int row = c / 96, f4 = c % 96;
    const float* sp;
    if (f4 < 32)       sp = nbuf + (size_t)slds[row] * DD + f4 * 4;
    else if (f4 < 64)  sp = nbuf + (size_t)dlds[row] * DD + (f4 - 32) * 4;
    else               sp = ebuf + (size_t)(e0 + row) * DD + (f4 - 64) * 4;
    float4 v = *(const float4*)sp;
    ushort4 hv;
    hv.x = f2bf(v.x); hv.y = f2bf(v.y); hv.z = f2bf(v.z); hv.w = f2bf(v.w);
    int slot = (f4 >> 1) ^ (row & 15);
    *(ushort4*)&Alds[row * 384 + slot * 8 + (f4 & 1) * 4] = hv;
  }
  __syncthreads();

  const f32x4 z = {0.f, 0.f, 0.f, 0.f};
  const int cbA = wv * 2, cbB = wv * 2 + 1;

  // ---- GEMM1: [64x384] @ w0[384x128] ----
  f32x4 acc[4][2];
#pragma unroll
  for (int rb = 0; rb < 4; ++rb) { acc[rb][0] = z; acc[rb][1] = z; }
#pragma unroll
  for (int kt = 0; kt < 12; ++kt) {
    bf16x8 bA = *(const bf16x8*)(w0 + (size_t)((cbA * 12 + kt) * 64 + lane) * 8);
    bf16x8 bB = *(const bf16x8*)(w0 + (size_t)((cbB * 12 + kt) * 64 + lane) * 8);
#pragma unroll
    for (int rb = 0; rb < 4; ++rb) {
      int row = rb * 16 + l15;
      bf16x8 a = *(const bf16x8*)&Alds[row * 384 + (((kt * 4 + l4) ^ (row & 15)) * 8)];
      acc[rb][0] = mfma16(a, bA, acc[rb][0]);
      acc[rb][1] = mfma16(a, bB, acc[rb][1]);
    }
  }
  __syncthreads();   // all Alds reads done before hidden tile overwrites it
  // h1 = relu(acc + b0) -> Hlds
  {
    float biasA = b0[cbA * 16 + l15], biasB = b0[cbB * 16 + l15];
#pragma unroll
    for (int cbi = 0; cbi < 2; ++cbi) {
      int col = (wv * 2 + cbi) * 16 + l15;
      float bias = cbi ? biasB : biasA;
#pragma unroll
      for (int rb = 0; rb < 4; ++rb)
#pragma unroll
        for (int r = 0; r < 4; ++r) {
          int row = rb * 16 + l4 * 4 + r;
          float v = fmaxf(acc[rb][cbi][r] + bias, 0.f);
          Hlds[row * 128 + (((col >> 3) ^ (row & 15)) * 8) + (col & 7)] = f2bf(v);
        }
    }
  }
  __syncthreads();

  // ---- GEMM2: [64x128] @ w1[128x128] ----
#pragma unroll
  for (int rb = 0; rb < 4; ++rb) { acc[rb][0] = z; acc[rb][1] = z; }
#pragma unroll
  for (int kt = 0; kt < 4; ++kt) {
    bf16x8 bA = *(const bf16x8*)(w1 + (size_t)((cbA * 4 + kt) * 64 + lane) * 8);
    bf16x8 bB = *(const bf16x8*)(w1 + (size_t)((cbB * 4 + kt) * 64 + lane) * 8);
#pragma unroll
    for (int rb = 0; rb < 4; ++rb) {
      int row = rb * 16 + l15;
      bf16x8 a = *(const bf16x8*)&Hlds[row * 128 + (((kt * 4 + l4) ^ (row & 15)) * 8)];
      acc[rb][0] = mfma16(a, bA, acc[rb][0]);
      acc[rb][1] = mfma16(a, bB, acc[rb][1]);
    }
  }
  __syncthreads();   // all reads of Hlds done
  {
    float biasA = b1[cbA * 16 + l15], biasB = b1[cbB * 16 + l15];
#pragma unroll
    for (int cbi = 0; cbi < 2; ++cbi) {
      int col = (wv * 2 + cbi) * 16 + l15;
      float bias = cbi ? biasB : biasA;
#pragma unroll
      for (int rb = 0; rb < 4; ++rb)
#pragma unroll
        for (int r = 0; r < 4; ++r) {
          int row = rb * 16 + l4 * 4 + r;
          float v = fmaxf(acc[rb][cbi][r] + bias, 0.f);
          Hlds[row * 128 + (((col >> 3) ^ (row & 15)) * 8) + (col & 7)] = f2bf(v);
        }
    }
  }
  __syncthreads();

  // ---- GEMM3: [64x128] @ w2[128x128], + b2 + residual, store ----
#pragma unroll
  for (int rb = 0; rb < 4; ++rb) { acc[rb][0] = z; acc[rb][1] = z; }
#pragma unroll
  for (int kt = 0; kt < 4; ++kt) {
    bf16x8 bA = *(const bf16x8*)(w2 + (size_t)((cbA * 4 + kt) * 64 + lane) * 8);
    bf16x8 bB = *(const bf16x8*)(w2 + (size_t)((cbB * 4 + kt) * 64 + lane) * 8);
#pragma unroll
    for (int rb = 0; rb < 4; ++rb) {
      int row = rb * 16 + l15;
      bf16x8 a = *(const bf16x8*)&Hlds[row * 128 + (((kt * 4 + l4) ^ (row & 15)) * 8)];
      acc[rb][0] = mfma16(a, bA, acc[rb][0]);
      acc[rb][1] = mfma16(a, bB, acc[rb][1]);
    }
  }
  {
#pragma unroll
    for (int cbi = 0; cbi < 2; ++cbi) {
      int col = (wv * 2 + cbi) * 16 + l15;
      float bias = b2[col];
#pragma unroll
      for (int rb = 0; rb < 4; ++rb)
#pragma unroll
        for (int r = 0; r < 4; ++r) {
          int row = rb * 16 + l4 * 4 + r;
          size_t off = (size_t)(e0 + row) * DD + col;
          ebuf[off] = ebuf[off] + acc[rb][cbi][r] + bias;
        }
    }
  }
}

// ---------------- node kernel: 64 nodes x 128 out per block ----------------
// CSR gather-sum replaces the atomic scatter: each wave owns 16 node-rows,
// sums incoming edge rows (coalesced 512B reads) in fp32 registers.
__global__ __launch_bounds__(256) void node_kernel(
    float* __restrict__ nbuf, const float* __restrict__ ebuf,
    const int* __restrict__ row_start, const int* __restrict__ eidx,
    const ushort* __restrict__ w0, const float* __restrict__ b0,
    const ushort* __restrict__ w1, const float* __restrict__ b1,
    const ushort* __restrict__ w2, const float* __restrict__ b2) {
  __shared__ ushort Alds[64 * 256];
  __shared__ ushort Hlds[64 * 128];

  const int tid = threadIdx.x;
  const int n0 = blockIdx.x * 64;
  const int lane = tid & 63, wv = tid >> 6;
  const int l15 = lane & 15, l4 = lane >> 4;

  // stage n (cols 0..127)
#pragma unroll
  for (int i = 0; i < 8; ++i) {
    int c = i * 256 + tid;
    int row = c >> 5, f4 = c & 31;
    int node = n0 + row;
    float4 v;
    if (node < NNODES) v = *(const float4*)(nbuf + (size_t)node * DD + f4 * 4);
    else { v.x = v.y = v.z = v.w = 0.f; }
    ushort4 hv;
    hv.x = f2bf(v.x); hv.y = f2bf(v.y); hv.z = f2bf(v.z); hv.w = f2bf(v.w);
    int slot = (f4 >> 1) ^ (row & 15);
    *(ushort4*)&Alds[row * 256 + slot * 8 + (f4 & 1) * 4] = hv;
  }

  // aggregate incoming edges (cols 128..255); wave wv owns rows wv*16..wv*16+15
  for (int r = 0; r < 16; ++r) {
    int row = wv * 16 + r;
    int node = n0 + row;
    float sx = 0.f, sy = 0.f, tx = 0.f, ty = 0.f;
    if (node < NNODES) {
      int jb = row_start[node], je = row_start[node + 1];
      int j = jb;
      for (; j + 1 < je; j += 2) {
        int ea = eidx[j], eb2i = eidx[j + 1];
        float2 va = *(const float2*)(ebuf + (size_t)ea * DD + lane * 2);
        float2 vb = *(const float2*)(ebuf + (size_t)eb2i * DD + lane * 2);
        sx += va.x; sy += va.y;
        tx += vb.x; ty += vb.y;
      }
      if (j < je) {
        int ea = eidx[j];
        float2 va = *(const float2*)(ebuf + (size_t)ea * DD + lane * 2);
        sx += va.x; sy += va.y;
      }
    }
    sx += tx; sy += ty;
    int c0 = 128 + lane * 2;
    int slot = (c0 >> 3) ^ (row & 15);
    ushort2 h;
    h.x = f2bf(sx); h.y = f2bf(sy);
    *(ushort2*)&Alds[row * 256 + slot * 8 + (c0 & 7)] = h;
  }
  __syncthreads();

  const f32x4 z = {0.f, 0.f, 0.f, 0.f};
  const int cbA = wv * 2, cbB = wv * 2 + 1;

  // ---- GEMM1: [64x256] @ nw0[256x128] ----
  f32x4 acc[4][2];
#pragma unroll
  for (int rb = 0; rb < 4; ++rb) { acc[rb][0] = z; acc[rb][1] = z; }
#pragma unroll
  for (int kt = 0; kt < 8; ++kt) {
    bf16x8 bA = *(const bf16x8*)(w0 + (size_t)((cbA * 8 + kt) * 64 + lane) * 8);
    bf16x8 bB = *(const bf16x8*)(w0 + (size_t)((cbB * 8 + kt) * 64 + lane) * 8);
#pragma unroll
    for (int rb = 0; rb < 4; ++rb) {
      int row = rb * 16 + l15;
      bf16x8 a = *(const bf16x8*)&Alds[row * 256 + (((kt * 4 + l4) ^ (row & 15)) * 8)];
      acc[rb][0] = mfma16(a, bA, acc[rb][0]);
      acc[rb][1] = mfma16(a, bB, acc[rb][1]);
    }
  }
  {
    float biasA = b0[cbA * 16 + l15], biasB = b0[cbB * 16 + l15];
#pragma unroll
    for (int cbi = 0; cbi < 2; ++cbi) {
      int col = (wv * 2 + cbi) * 16 + l15;
      float bias = cbi ? biasB : biasA;
#pragma unroll
      for (int rb = 0; rb < 4; ++rb)
#pragma unroll
        for (int r = 0; r < 4; ++r) {
          int row = rb * 16 + l4 * 4 + r;
          float v = fmaxf(acc[rb][cbi][r] + bias, 0.f);
          Hlds[row * 128 + (((col >> 3) ^ (row & 15)) * 8) + (col & 7)] = f2bf(v);
        }
    }
  }
  __syncthreads();

  // ---- GEMM2 ----
#pragma unroll
  for (int rb = 0; rb < 4; ++rb) { acc[rb][0] = z; acc[rb][1] = z; }
#pragma unroll
  for (int kt = 0; kt < 4; ++kt) {
    bf16x8 bA = *(const bf16x8*)(w1 + (size_t)((cbA * 4 + kt) * 64 + lane) * 8);
    bf16x8 bB = *(const bf16x8*)(w1 + (size_t)((cbB * 4 + kt) * 64 + lane) * 8);
#pragma unroll
    for (int rb = 0; rb < 4; ++rb) {
      int row = rb * 16 + l15;
      bf16x8 a = *(const bf16x8*)&Hlds[row * 128 + (((kt * 4 + l4) ^ (row & 15)) * 8)];
      acc[rb][0] = mfma16(a, bA, acc[rb][0]);
      acc[rb][1] = mfma16(a, bB, acc[rb][1]);
    }
  }
  __syncthreads();
  {
    float biasA = b1[cbA * 16 + l15], biasB = b1[cbB * 16 + l15];
#pragma unroll
    for (int cbi = 0; cbi < 2; ++cbi) {
      int col = (wv * 2 + cbi) * 16 + l15;
      float bias = cbi ? biasB : biasA;
#pragma unroll
      for (int rb = 0; rb < 4; ++rb)
#pragma unroll
        for (int r = 0; r < 4; ++r) {
          int row = rb * 16 + l4 * 4 + r;
          float v = fmaxf(acc[rb][cbi][r] + bias, 0.f);
          Hlds[row * 128 + (((col >> 3) ^ (row & 15)) * 8) + (col & 7)] = f2bf(v);
        }
    }
  }
  __syncthreads();

  // ---- GEMM3 + residual ----
#pragma unroll
  for (int rb = 0; rb < 4; ++rb) { acc[rb][0] = z; acc[rb][1] = z; }
#pragma unroll
  for (int kt = 0; kt < 4; ++kt) {
    bf16x8 bA = *(const bf16x8*)(w2 + (size_t)((cbA * 4 + kt) * 64 + lane) * 8);
    bf16x8 bB = *(const bf16x8*)(w2 + (size_t)((cbB * 4 + kt) * 64 + lane) * 8);
#pragma unroll
    for (int rb = 0; rb < 4; ++rb) {
      int row = rb * 16 + l15;
      bf16x8 a = *(const bf16x8*)&Hlds[row * 128 + (((kt * 4 + l4) ^ (row & 15)) * 8)];
      acc[rb][0] = mfma16(a, bA, acc[rb][0]);
      acc[rb][1] = mfma16(a, bB, acc[rb][1]);
    }
  }
  {
#pragma unroll
    for (int cbi = 0; cbi < 2; ++cbi) {
      int col = (wv * 2 + cbi) * 16 + l15;
      float bias = b2[col];
#pragma unroll
      for (int rb = 0; rb < 4; ++rb)
#pragma unroll
        for (int r = 0; r < 4; ++r) {
          int row = rb * 16 + l4 * 4 + r;
          int node = n0 + row;
          if (node < NNODES) {
            size_t off = (size_t)node * DD + col;
            nbuf[off] = nbuf[off] + acc[rb][cbi][r] + bias;
          }
        }
    }
  }
}

extern "C" void kernel_launch(void* const* d_in, const int* in_sizes, int n_in,
                              void* d_out, int out_size, void* d_ws, size_t ws_size,
                              hipStream_t stream) {
  const float* node_f = (const float*)d_in[0];
  const float* edge_f = (const float*)d_in[1];
  const int* srcI = (const int*)d_in[2];
  const int* dstI = (const int*)d_in[3];
  const float* ew0 = (const float*)d_in[4];
  const float* eb0 = (const float*)d_in[5];
  const float* ew1 = (const float*)d_in[6];
  const float* eb1 = (const float*)d_in[7];
  const float* ew2 = (const float*)d_in[8];
  const float* eb2 = (const float*)d_in[9];
  const float* nw0 = (const float*)d_in[10];
  const float* nb0 = (const float*)d_in[11];
  const float* nw1 = (const float*)d_in[12];
  const float* nb1 = (const float*)d_in[13];
  const float* nw2 = (const float*)d_in[14];
  const float* nb2 = (const float*)d_in[15];

  char* ws = (char*)d_ws;
  const size_t EB = (size_t)NEDGES * DD * 4;   // 81,920,000
  const size_t NB = (size_t)NNODES * DD * 4;   //  5,120,000
  float* ebuf = (float*)ws;
  float* nbuf = (float*)(ws + EB);
  ushort* pw  = (ushort*)(ws + EB + NB);
  ushort* pew0 = pw;                    // 15*384*128
  ushort* pew1 = pew0 + 737280;         // 15*128*128
  ushort* pew2 = pew1 + 245760;
  ushort* pnw0 = pew2 + 245760;         // 15*256*128
  ushort* pnw1 = pnw0 + 491520;
  ushort* pnw2 = pnw1 + 245760;
  const size_t WBYTES = 2211840ull * 2;  // total packed-weight bytes
  int* eidx      = (int*)(ws + EB + NB + WBYTES);
  int* cnt       = eidx + NEDGES;
  int* row_start = cnt + NNODES;
  int* cursor    = row_start + NNODES + 1;

  // pack all weights to bf16 fragment layout
  {
    struct { const float* s; ushort* d; int K; } packs[6] = {
      {ew0, pew0, 384}, {ew1, pew1, 128}, {ew2, pew2, 128},
      {nw0, pnw0, 256}, {nw1, pnw1, 128}, {nw2, pnw2, 128},
    };
    for (int i = 0; i < 6; ++i) {
      int total = PP * packs[i].K * 128;
      pack_w<<<(total + 255) / 256, 256, 0, stream>>>(packs[i].s, packs[i].d,
                                                      packs[i].K, total);
    }
  }

  // CSR build (graph is static across layers)
  hipMemsetAsync(cnt, 0, NNODES * sizeof(int), stream);
  hist_kernel<<<(NEDGES + 255) / 256, 256, 0, stream>>>(dstI, cnt);
  scan_kernel<<<1, 256, 0, stream>>>(cnt, row_start, cursor);
  scatter_kernel<<<(NEDGES + 255) / 256, 256, 0, stream>>>(dstI, cursor, eidx);

  hipMemcpyAsync(ebuf, edge_f, EB, hipMemcpyDeviceToDevice, stream);
  hipMemcpyAsync(nbuf, node_f, NB, hipMemcpyDeviceToDevice, stream);

  const int eblocks = NEDGES / 64;                 // 2500
  const int nblocks = (NNODES + 63) / 64;          // 157

  for (int p = 0; p < PP; ++p) {
    edge_kernel<<<eblocks, 256, 0, stream>>>(
        nbuf, ebuf, srcI, dstI,
        pew0 + (size_t)p * 49152, eb0 + (size_t)p * DD,
        pew1 + (size_t)p * 16384, eb1 + (size_t)p * DD,
        pew2 + (size_t)p * 16384, eb2 + (size_t)p * DD);
    node_kernel<<<nblocks, 256, 0, stream>>>(
        nbuf, ebuf, row_start, eidx,
        pnw0 + (size_t)p * 32768, nb0 + (size_t)p * DD,
        pnw1 + (size_t)p * 16384, nb1 + (size_t)p * DD,
        pnw2 + (size_t)p * 16384, nb2 + (size_t)p * DD);
  }

  hipMemcpyAsync(d_out, nbuf, NB, hipMemcpyDeviceToDevice, stream);
}

// Round 3
// 2356.708 us; speedup vs baseline: 1.6465x; 1.6465x over previous
//
#include <hip/hip_runtime.h>

#define DD 128
#define PP 15
#define NNODES 10000
#define NEDGES 160000

typedef __attribute__((ext_vector_type(8))) short bf16x8;
typedef __attribute__((ext_vector_type(4))) float f32x4;

__device__ inline ushort f2bf(float f) {
  unsigned u = __builtin_bit_cast(unsigned, f);
  u += 0x7FFFu + ((u >> 16) & 1u);   // round-to-nearest-even
  return (ushort)(u >> 16);
}

__device__ inline f32x4 mfma16(bf16x8 a, bf16x8 b, f32x4 c) {
  return __builtin_amdgcn_mfma_f32_16x16x32_bf16(a, b, c, 0, 0, 0);
}

// Pack fp32 weight [P][K][128] into bf16 MFMA B-fragment order:
// out[p][cb][kt][lane][e] = w[p][kt*32 + (lane>>4)*8 + e][cb*16 + (lane&15)]
__global__ __launch_bounds__(256) void pack_w(const float* __restrict__ w,
                                              ushort* __restrict__ out,
                                              int K, int total) {
  int i = blockIdx.x * 256 + threadIdx.x;
  if (i >= total) return;
  int per = K * 128;
  int p = i / per, j = i % per;
  int e = j & 7;
  int lane = (j >> 3) & 63;
  int t = j >> 9;               // cb*nkt + kt
  int nkt = K >> 5;
  int kt = t % nkt, cb = t / nkt;
  int k = kt * 32 + ((lane >> 4) << 3) + e;
  int n = (cb << 4) + (lane & 15);
  out[i] = f2bf(w[(size_t)p * per + (size_t)k * 128 + n]);
}

// copy fp32 input -> fp32 working buf + bf16 shadow
__global__ __launch_bounds__(256) void cvt_init(const float* __restrict__ in,
                                                float* __restrict__ out_f,
                                                ushort* __restrict__ out_bf, int n4) {
  int i = blockIdx.x * 256 + threadIdx.x;
  if (i >= n4) return;
  float4 v = ((const float4*)in)[i];
  ((float4*)out_f)[i] = v;
  ushort4 h;
  h.x = f2bf(v.x); h.y = f2bf(v.y); h.z = f2bf(v.z); h.w = f2bf(v.w);
  ((ushort4*)out_bf)[i] = h;
}

// ---------------- CSR build: histogram + scan + scatter ----------------
__global__ __launch_bounds__(256) void hist_kernel(const int* __restrict__ dst,
                                                   int* __restrict__ cnt) {
  int i = blockIdx.x * 256 + threadIdx.x;
  if (i < NEDGES) atomicAdd(&cnt[dst[i]], 1);
}

__global__ __launch_bounds__(256) void scan_kernel(const int* __restrict__ cnt,
                                                   int* __restrict__ row_start,
                                                   int* __restrict__ cursor) {
  __shared__ int part[256];
  const int CH = (NNODES + 255) / 256;     // 40
  int t = threadIdx.x;
  int beg = t * CH, end = min(beg + CH, NNODES);
  int s = 0;
  for (int i = beg; i < end; ++i) s += cnt[i];
  part[t] = s;
  __syncthreads();
  for (int off = 1; off < 256; off <<= 1) {
    int v = (t >= off) ? part[t - off] : 0;
    __syncthreads();
    part[t] += v;
    __syncthreads();
  }
  int run = part[t] - s;     // exclusive prefix
  for (int i = beg; i < end; ++i) {
    row_start[i] = run;
    cursor[i] = run;
    run += cnt[i];
  }
  if (t == 255) row_start[NNODES] = NEDGES;
}

__global__ __launch_bounds__(256) void scatter_kernel(const int* __restrict__ dst,
                                                      int* __restrict__ cursor,
                                                      int* __restrict__ eidx) {
  int i = blockIdx.x * 256 + threadIdx.x;
  if (i < NEDGES) {
    int pos = atomicAdd(&cursor[dst[i]], 1);
    eidx[pos] = i;
  }
}

// ---------------- aggregation: one wave per node, 4-deep ILP ----------------
__global__ __launch_bounds__(256) void agg_kernel(const float* __restrict__ ebuf,
                                                  ushort* __restrict__ abf,
                                                  const int* __restrict__ row_start,
                                                  const int* __restrict__ eidx) {
  int wv = threadIdx.x >> 6, lane = threadIdx.x & 63;
  int node = blockIdx.x * 4 + wv;
  if (node >= NNODES) return;
  int jb = row_start[node], je = row_start[node + 1];
  float ax = 0.f, ay = 0.f, bx = 0.f, by = 0.f;
  float cx = 0.f, cy = 0.f, dx = 0.f, dy = 0.f;
  int j = jb;
  for (; j + 3 < je; j += 4) {
    int e0 = eidx[j], e1 = eidx[j + 1], e2 = eidx[j + 2], e3 = eidx[j + 3];
    float2 v0 = *(const float2*)(ebuf + (size_t)e0 * DD + lane * 2);
    float2 v1 = *(const float2*)(ebuf + (size_t)e1 * DD + lane * 2);
    float2 v2 = *(const float2*)(ebuf + (size_t)e2 * DD + lane * 2);
    float2 v3 = *(const float2*)(ebuf + (size_t)e3 * DD + lane * 2);
    ax += v0.x; ay += v0.y;
    bx += v1.x; by += v1.y;
    cx += v2.x; cy += v2.y;
    dx += v3.x; dy += v3.y;
  }
  for (; j < je; ++j) {
    int e0 = eidx[j];
    float2 v0 = *(const float2*)(ebuf + (size_t)e0 * DD + lane * 2);
    ax += v0.x; ay += v0.y;
  }
  float sx = (ax + bx) + (cx + dx);
  float sy = (ay + by) + (cy + dy);
  ushort2 h;
  h.x = f2bf(sx); h.y = f2bf(sy);
  *(ushort2*)&abf[(size_t)node * DD + lane * 2] = h;
}

// ---------------- edge kernel: 64 edges x 128 out per block, 4 waves ----------------
// bf16-shadow staging (no conversions); Hlds aliased onto Alds -> 48.5 KB LDS.
__global__ __launch_bounds__(256) void edge_kernel(
    const ushort* __restrict__ nbf, float* __restrict__ ebuf,
    ushort* __restrict__ ebf,
    const int* __restrict__ srcI, const int* __restrict__ dstI,
    const ushort* __restrict__ w0, const float* __restrict__ b0,
    const ushort* __restrict__ w1, const float* __restrict__ b1,
    const ushort* __restrict__ w2, const float* __restrict__ b2) {
  __shared__ ushort S[64 * 384];      // cat tile (swizzled); later reused as hidden tile
  __shared__ int slds[64], dlds[64];
  ushort* Alds = S;
  ushort* Hlds = S;

  const int tid = threadIdx.x;
  const int e0 = blockIdx.x * 64;
  const int lane = tid & 63, wv = tid >> 6;
  const int l15 = lane & 15, l4 = lane >> 4;

  if (tid < 64) slds[tid] = srcI[e0 + tid];
  else if (tid < 128) dlds[tid - 64] = dstI[e0 + tid - 64];
  __syncthreads();

  // stage cat = [n[src] | n[dst] | e] (already bf16) into Alds, 16B chunks
#pragma unroll
  for (int i = 0; i < 12; ++i) {
    int c = i * 256 + tid;          // 0..3071
    int row = c / 48, f8 = c % 48;  // f8: 16B chunk within 768B row
    const ushort* sp;
    if (f8 < 16)       sp = nbf + (size_t)slds[row] * DD + f8 * 8;
    else if (f8 < 32)  sp = nbf + (size_t)dlds[row] * DD + (f8 - 16) * 8;
    else               sp = ebf + (size_t)(e0 + row) * DD + (f8 - 32) * 8;
    bf16x8 v = *(const bf16x8*)sp;
    int slot = f8 ^ (row & 15);
    *(bf16x8*)&Alds[row * 384 + slot * 8] = v;
  }
  __syncthreads();

  const f32x4 z = {0.f, 0.f, 0.f, 0.f};
  const int cbA = wv * 2, cbB = wv * 2 + 1;

  // ---- GEMM1: [64x384] @ w0[384x128] ----
  f32x4 acc[4][2];
#pragma unroll
  for (int rb = 0; rb < 4; ++rb) { acc[rb][0] = z; acc[rb][1] = z; }
#pragma unroll
  for (int kt = 0; kt < 12; ++kt) {
    bf16x8 bA = *(const bf16x8*)(w0 + (size_t)((cbA * 12 + kt) * 64 + lane) * 8);
    bf16x8 bB = *(const bf16x8*)(w0 + (size_t)((cbB * 12 + kt) * 64 + lane) * 8);
#pragma unroll
    for (int rb = 0; rb < 4; ++rb) {
      int row = rb * 16 + l15;
      bf16x8 a = *(const bf16x8*)&Alds[row * 384 + (((kt * 4 + l4) ^ (row & 15)) * 8)];
      acc[rb][0] = mfma16(a, bA, acc[rb][0]);
      acc[rb][1] = mfma16(a, bB, acc[rb][1]);
    }
  }
  __syncthreads();   // all Alds reads done before hidden tile overwrites it
  // h1 = relu(acc + b0) -> Hlds
  {
    float biasA = b0[cbA * 16 + l15], biasB = b0[cbB * 16 + l15];
#pragma unroll
    for (int cbi = 0; cbi < 2; ++cbi) {
      int col = (wv * 2 + cbi) * 16 + l15;
      float bias = cbi ? biasB : biasA;
#pragma unroll
      for (int rb = 0; rb < 4; ++rb)
#pragma unroll
        for (int r = 0; r < 4; ++r) {
          int row = rb * 16 + l4 * 4 + r;
          float v = fmaxf(acc[rb][cbi][r] + bias, 0.f);
          Hlds[row * 128 + (((col >> 3) ^ (row & 15)) * 8) + (col & 7)] = f2bf(v);
        }
    }
  }
  __syncthreads();

  // ---- GEMM2: [64x128] @ w1[128x128] ----
#pragma unroll
  for (int rb = 0; rb < 4; ++rb) { acc[rb][0] = z; acc[rb][1] = z; }
#pragma unroll
  for (int kt = 0; kt < 4; ++kt) {
    bf16x8 bA = *(const bf16x8*)(w1 + (size_t)((cbA * 4 + kt) * 64 + lane) * 8);
    bf16x8 bB = *(const bf16x8*)(w1 + (size_t)((cbB * 4 + kt) * 64 + lane) * 8);
#pragma unroll
    for (int rb = 0; rb < 4; ++rb) {
      int row = rb * 16 + l15;
      bf16x8 a = *(const bf16x8*)&Hlds[row * 128 + (((kt * 4 + l4) ^ (row & 15)) * 8)];
      acc[rb][0] = mfma16(a, bA, acc[rb][0]);
      acc[rb][1] = mfma16(a, bB, acc[rb][1]);
    }
  }
  __syncthreads();   // all reads of Hlds done
  {
    float biasA = b1[cbA * 16 + l15], biasB = b1[cbB * 16 + l15];
#pragma unroll
    for (int cbi = 0; cbi < 2; ++cbi) {
      int col = (wv * 2 + cbi) * 16 + l15;
      float bias = cbi ? biasB : biasA;
#pragma unroll
      for (int rb = 0; rb < 4; ++rb)
#pragma unroll
        for (int r = 0; r < 4; ++r) {
          int row = rb * 16 + l4 * 4 + r;
          float v = fmaxf(acc[rb][cbi][r] + bias, 0.f);
          Hlds[row * 128 + (((col >> 3) ^ (row & 15)) * 8) + (col & 7)] = f2bf(v);
        }
    }
  }
  __syncthreads();

  // ---- GEMM3: [64x128] @ w2[128x128], + b2 + residual, store fp32 + bf16 ----
#pragma unroll
  for (int rb = 0; rb < 4; ++rb) { acc[rb][0] = z; acc[rb][1] = z; }
#pragma unroll
  for (int kt = 0; kt < 4; ++kt) {
    bf16x8 bA = *(const bf16x8*)(w2 + (size_t)((cbA * 4 + kt) * 64 + lane) * 8);
    bf16x8 bB = *(const bf16x8*)(w2 + (size_t)((cbB * 4 + kt) * 64 + lane) * 8);
#pragma unroll
    for (int rb = 0; rb < 4; ++rb) {
      int row = rb * 16 + l15;
      bf16x8 a = *(const bf16x8*)&Hlds[row * 128 + (((kt * 4 + l4) ^ (row & 15)) * 8)];
      acc[rb][0] = mfma16(a, bA, acc[rb][0]);
      acc[rb][1] = mfma16(a, bB, acc[rb][1]);
    }
  }
  {
#pragma unroll
    for (int cbi = 0; cbi < 2; ++cbi) {
      int col = (wv * 2 + cbi) * 16 + l15;
      float bias = b2[col];
#pragma unroll
      for (int rb = 0; rb < 4; ++rb)
#pragma unroll
        for (int r = 0; r < 4; ++r) {
          int row = rb * 16 + l4 * 4 + r;
          size_t off = (size_t)(e0 + row) * DD + col;
          float res = ebuf[off] + acc[rb][cbi][r] + bias;
          ebuf[off] = res;
          ebf[off] = f2bf(res);
        }
    }
  }
}

// ---------------- node kernel: 64 nodes x 128 out per block ----------------
__global__ __launch_bounds__(256) void node_kernel(
    float* __restrict__ nbuf, ushort* __restrict__ nbf,
    const ushort* __restrict__ abf,
    const ushort* __restrict__ w0, const float* __restrict__ b0,
    const ushort* __restrict__ w1, const float* __restrict__ b1,
    const ushort* __restrict__ w2, const float* __restrict__ b2) {
  __shared__ ushort Alds[64 * 256];
  __shared__ ushort Hlds[64 * 128];

  const int tid = threadIdx.x;
  const int n0 = blockIdx.x * 64;
  const int lane = tid & 63, wv = tid >> 6;
  const int l15 = lane & 15, l4 = lane >> 4;

  // stage cat_n = [n | agg] (both already bf16)
#pragma unroll
  for (int i = 0; i < 8; ++i) {
    int c = i * 256 + tid;          // 0..2047
    int row = c >> 5, f8 = c & 31;
    int node = n0 + row;
    bf16x8 v = {0, 0, 0, 0, 0, 0, 0, 0};
    if (node < NNODES) {
      const ushort* sp = (f8 < 16) ? nbf + (size_t)node * DD + f8 * 8
                                   : abf + (size_t)node * DD + (f8 - 16) * 8;
      v = *(const bf16x8*)sp;
    }
    int slot = f8 ^ (row & 15);
    *(bf16x8*)&Alds[row * 256 + slot * 8] = v;
  }
  __syncthreads();

  const f32x4 z = {0.f, 0.f, 0.f, 0.f};
  const int cbA = wv * 2, cbB = wv * 2 + 1;

  // ---- GEMM1: [64x256] @ nw0[256x128] ----
  f32x4 acc[4][2];
#pragma unroll
  for (int rb = 0; rb < 4; ++rb) { acc[rb][0] = z; acc[rb][1] = z; }
#pragma unroll
  for (int kt = 0; kt < 8; ++kt) {
    bf16x8 bA = *(const bf16x8*)(w0 + (size_t)((cbA * 8 + kt) * 64 + lane) * 8);
    bf16x8 bB = *(const bf16x8*)(w0 + (size_t)((cbB * 8 + kt) * 64 + lane) * 8);
#pragma unroll
    for (int rb = 0; rb < 4; ++rb) {
      int row = rb * 16 + l15;
      bf16x8 a = *(const bf16x8*)&Alds[row * 256 + (((kt * 4 + l4) ^ (row & 15)) * 8)];
      acc[rb][0] = mfma16(a, bA, acc[rb][0]);
      acc[rb][1] = mfma16(a, bB, acc[rb][1]);
    }
  }
  {
    float biasA = b0[cbA * 16 + l15], biasB = b0[cbB * 16 + l15];
#pragma unroll
    for (int cbi = 0; cbi < 2; ++cbi) {
      int col = (wv * 2 + cbi) * 16 + l15;
      float bias = cbi ? biasB : biasA;
#pragma unroll
      for (int rb = 0; rb < 4; ++rb)
#pragma unroll
        for (int r = 0; r < 4; ++r) {
          int row = rb * 16 + l4 * 4 + r;
          float v = fmaxf(acc[rb][cbi][r] + bias, 0.f);
          Hlds[row * 128 + (((col >> 3) ^ (row & 15)) * 8) + (col & 7)] = f2bf(v);
        }
    }
  }
  __syncthreads();

  // ---- GEMM2 ----
#pragma unroll
  for (int rb = 0; rb < 4; ++rb) { acc[rb][0] = z; acc[rb][1] = z; }
#pragma unroll
  for (int kt = 0; kt < 4; ++kt) {
    bf16x8 bA = *(const bf16x8*)(w1 + (size_t)((cbA * 4 + kt) * 64 + lane) * 8);
    bf16x8 bB = *(const bf16x8*)(w1 + (size_t)((cbB * 4 + kt) * 64 + lane) * 8);
#pragma unroll
    for (int rb = 0; rb < 4; ++rb) {
      int row = rb * 16 + l15;
      bf16x8 a = *(const bf16x8*)&Hlds[row * 128 + (((kt * 4 + l4) ^ (row & 15)) * 8)];
      acc[rb][0] = mfma16(a, bA, acc[rb][0]);
      acc[rb][1] = mfma16(a, bB, acc[rb][1]);
    }
  }
  __syncthreads();
  {
    float biasA = b1[cbA * 16 + l15], biasB = b1[cbB * 16 + l15];
#pragma unroll
    for (int cbi = 0; cbi < 2; ++cbi) {
      int col = (wv * 2 + cbi) * 16 + l15;
      float bias = cbi ? biasB : biasA;
#pragma unroll
      for (int rb = 0; rb < 4; ++rb)
#pragma unroll
        for (int r = 0; r < 4; ++r) {
          int row = rb * 16 + l4 * 4 + r;
          float v = fmaxf(acc[rb][cbi][r] + bias, 0.f);
          Hlds[row * 128 + (((col >> 3) ^ (row & 15)) * 8) + (col & 7)] = f2bf(v);
        }
    }
  }
  __syncthreads();

  // ---- GEMM3 + residual ----
#pragma unroll
  for (int rb = 0; rb < 4; ++rb) { acc[rb][0] = z; acc[rb][1] = z; }
#pragma unroll
  for (int kt = 0; kt < 4; ++kt) {
    bf16x8 bA = *(const bf16x8*)(w2 + (size_t)((cbA * 4 + kt) * 64 + lane) * 8);
    bf16x8 bB = *(const bf16x8*)(w2 + (size_t)((cbB * 4 + kt) * 64 + lane) * 8);
#pragma unroll
    for (int rb = 0; rb < 4; ++rb) {
      int row = rb * 16 + l15;
      bf16x8 a = *(const bf16x8*)&Hlds[row * 128 + (((kt * 4 + l4) ^ (row & 15)) * 8)];
      acc[rb][0] = mfma16(a, bA, acc[rb][0]);
      acc[rb][1] = mfma16(a, bB, acc[rb][1]);
    }
  }
  {
#pragma unroll
    for (int cbi = 0; cbi < 2; ++cbi) {
      int col = (wv * 2 + cbi) * 16 + l15;
      float bias = b2[col];
#pragma unroll
      for (int rb = 0; rb < 4; ++rb)
#pragma unroll
        for (int r = 0; r < 4; ++r) {
          int row = rb * 16 + l4 * 4 + r;
          int node = n0 + row;
          if (node < NNODES) {
            size_t off = (size_t)node * DD + col;
            float res = nbuf[off] + acc[rb][cbi][r] + bias;
            nbuf[off] = res;
            nbf[off] = f2bf(res);
          }
        }
    }
  }
}

extern "C" void kernel_launch(void* const* d_in, const int* in_sizes, int n_in,
                              void* d_out, int out_size, void* d_ws, size_t ws_size,
                              hipStream_t stream) {
  const float* node_f = (const float*)d_in[0];
  const float* edge_f = (const float*)d_in[1];
  const int* srcI = (const int*)d_in[2];
  const int* dstI = (const int*)d_in[3];
  const float* ew0 = (const float*)d_in[4];
  const float* eb0 = (const float*)d_in[5];
  const float* ew1 = (const float*)d_in[6];
  const float* eb1 = (const float*)d_in[7];
  const float* ew2 = (const float*)d_in[8];
  const float* eb2 = (const float*)d_in[9];
  const float* nw0 = (const float*)d_in[10];
  const float* nb0 = (const float*)d_in[11];
  const float* nw1 = (const float*)d_in[12];
  const float* nb1 = (const float*)d_in[13];
  const float* nw2 = (const float*)d_in[14];
  const float* nb2 = (const float*)d_in[15];

  char* ws = (char*)d_ws;
  const size_t EB  = (size_t)NEDGES * DD * 4;   // 81,920,000
  const size_t NB  = (size_t)NNODES * DD * 4;   //  5,120,000
  const size_t EBH = (size_t)NEDGES * DD * 2;   // 40,960,000
  const size_t NBH = (size_t)NNODES * DD * 2;   //  2,560,000
  float*  ebuf = (float*)ws;
  float*  nbuf = (float*)(ws + EB);
  ushort* ebf  = (ushort*)(ws + EB + NB);
  ushort* nbf  = (ushort*)(ws + EB + NB + EBH);
  ushort* abf  = (ushort*)(ws + EB + NB + EBH + NBH);
  ushort* pw   = (ushort*)(ws + EB + NB + EBH + 2 * NBH);
  ushort* pew0 = pw;                    // 15*384*128
  ushort* pew1 = pew0 + 737280;         // 15*128*128
  ushort* pew2 = pew1 + 245760;
  ushort* pnw0 = pew2 + 245760;         // 15*256*128
  ushort* pnw1 = pnw0 + 491520;
  ushort* pnw2 = pnw1 + 245760;
  const size_t WBYTES = 2211840ull * 2;  // total packed-weight bytes
  int* eidx      = (int*)(ws + EB + NB + EBH + 2 * NBH + WBYTES);
  int* cnt       = eidx + NEDGES;
  int* row_start = cnt + NNODES;
  int* cursor    = row_start + NNODES + 1;

  // pack all weights to bf16 fragment layout
  {
    struct { const float* s; ushort* d; int K; } packs[6] = {
      {ew0, pew0, 384}, {ew1, pew1, 128}, {ew2, pew2, 128},
      {nw0, pnw0, 256}, {nw1, pnw1, 128}, {nw2, pnw2, 128},
    };
    for (int i = 0; i < 6; ++i) {
      int total = PP * packs[i].K * 128;
      pack_w<<<(total + 255) / 256, 256, 0, stream>>>(packs[i].s, packs[i].d,
                                                      packs[i].K, total);
    }
  }

  // CSR build (graph is static across layers)
  hipMemsetAsync(cnt, 0, NNODES * sizeof(int), stream);
  hist_kernel<<<(NEDGES + 255) / 256, 256, 0, stream>>>(dstI, cnt);
  scan_kernel<<<1, 256, 0, stream>>>(cnt, row_start, cursor);
  scatter_kernel<<<(NEDGES + 255) / 256, 256, 0, stream>>>(dstI, cursor, eidx);

  // init fp32 working copies + bf16 shadows
  {
    int en4 = NEDGES * DD / 4, nn4 = NNODES * DD / 4;
    cvt_init<<<(en4 + 255) / 256, 256, 0, stream>>>(edge_f, ebuf, ebf, en4);
    cvt_init<<<(nn4 + 255) / 256, 256, 0, stream>>>(node_f, nbuf, nbf, nn4);
  }

  const int eblocks = NEDGES / 64;                 // 2500
  const int nblocks = (NNODES + 63) / 64;          // 157
  const int ablocks = (NNODES + 3) / 4;            // 2500

  for (int p = 0; p < PP; ++p) {
    edge_kernel<<<eblocks, 256, 0, stream>>>(
        nbf, ebuf, ebf, srcI, dstI,
        pew0 + (size_t)p * 49152, eb0 + (size_t)p * DD,
        pew1 + (size_t)p * 16384, eb1 + (size_t)p * DD,
        pew2 + (size_t)p * 16384, eb2 + (size_t)p * DD);
    agg_kernel<<<ablocks, 256, 0, stream>>>(ebuf, abf, row_start, eidx);
    node_kernel<<<nblocks, 256, 0, stream>>>(
        nbuf, nbf, abf,
        pnw0 + (size_t)p * 32768, nb0 + (size_t)p * DD,
        pnw1 + (size_t)p * 16384, nb1 + (size_t)p * DD,
        pnw2 + (size_t)p * 16384, nb2 + (size_t)p * DD);
  }

  hipMemcpyAsync(d_out, nbuf, NB, hipMemcpyDeviceToDevice, stream);
}

// Round 4
// 1565.351 us; speedup vs baseline: 2.4789x; 1.5055x over previous
//
#include <hip/hip_runtime.h>

#define DD 128
#define PP 15
#define NNODES 10000
#define NEDGES 160000

typedef __attribute__((ext_vector_type(8))) short bf16x8;
typedef __attribute__((ext_vector_type(4))) float f32x4;

__device__ inline ushort f2bf(float f) {
  unsigned u = __builtin_bit_cast(unsigned, f);
  u += 0x7FFFu + ((u >> 16) & 1u);   // round-to-nearest-even
  return (ushort)(u >> 16);
}

__device__ inline float bf2f(ushort h) {
  unsigned u = ((unsigned)h) << 16;
  return __builtin_bit_cast(float, u);
}

__device__ inline f32x4 mfma16(bf16x8 a, bf16x8 b, f32x4 c) {
  return __builtin_amdgcn_mfma_f32_16x16x32_bf16(a, b, c, 0, 0, 0);
}

// Pack fp32 weight [P][K][128] into bf16 MFMA B-fragment order:
// out[p][cb][kt][lane][e] = w[p][kt*32 + (lane>>4)*8 + e][cb*16 + (lane&15)]
__global__ __launch_bounds__(256) void pack_w(const float* __restrict__ w,
                                              ushort* __restrict__ out,
                                              int K, int total) {
  int i = blockIdx.x * 256 + threadIdx.x;
  if (i >= total) return;
  int per = K * 128;
  int p = i / per, j = i % per;
  int e = j & 7;
  int lane = (j >> 3) & 63;
  int t = j >> 9;               // cb*nkt + kt
  int nkt = K >> 5;
  int kt = t % nkt, cb = t / nkt;
  int k = kt * 32 + ((lane >> 4) << 3) + e;
  int n = (cb << 4) + (lane & 15);
  out[i] = f2bf(w[(size_t)p * per + (size_t)k * 128 + n]);
}

// fp32 -> bf16 only (edge stream)
__global__ __launch_bounds__(256) void cvt_bf(const float* __restrict__ in,
                                              ushort* __restrict__ out, int n4) {
  int i = blockIdx.x * 256 + threadIdx.x;
  if (i >= n4) return;
  float4 v = ((const float4*)in)[i];
  ushort4 h;
  h.x = f2bf(v.x); h.y = f2bf(v.y); h.z = f2bf(v.z); h.w = f2bf(v.w);
  ((ushort4*)out)[i] = h;
}

// fp32 -> fp32 working + bf16 shadow (node stream)
__global__ __launch_bounds__(256) void cvt_init(const float* __restrict__ in,
                                                float* __restrict__ out_f,
                                                ushort* __restrict__ out_bf, int n4) {
  int i = blockIdx.x * 256 + threadIdx.x;
  if (i >= n4) return;
  float4 v = ((const float4*)in)[i];
  ((float4*)out_f)[i] = v;
  ushort4 h;
  h.x = f2bf(v.x); h.y = f2bf(v.y); h.z = f2bf(v.z); h.w = f2bf(v.w);
  ((ushort4*)out_bf)[i] = h;
}

// ---------------- CSR build: histogram + scan + scatter ----------------
__global__ __launch_bounds__(256) void hist_kernel(const int* __restrict__ dst,
                                                   int* __restrict__ cnt) {
  int i = blockIdx.x * 256 + threadIdx.x;
  if (i < NEDGES) atomicAdd(&cnt[dst[i]], 1);
}

__global__ __launch_bounds__(256) void scan_kernel(const int* __restrict__ cnt,
                                                   int* __restrict__ row_start,
                                                   int* __restrict__ cursor) {
  __shared__ int part[256];
  const int CH = (NNODES + 255) / 256;     // 40
  int t = threadIdx.x;
  int beg = t * CH, end = min(beg + CH, NNODES);
  int s = 0;
  for (int i = beg; i < end; ++i) s += cnt[i];
  part[t] = s;
  __syncthreads();
  for (int off = 1; off < 256; off <<= 1) {
    int v = (t >= off) ? part[t - off] : 0;
    __syncthreads();
    part[t] += v;
    __syncthreads();
  }
  int run = part[t] - s;     // exclusive prefix
  for (int i = beg; i < end; ++i) {
    row_start[i] = run;
    cursor[i] = run;
    run += cnt[i];
  }
  if (t == 255) row_start[NNODES] = NEDGES;
}

__global__ __launch_bounds__(256) void scatter_kernel(const int* __restrict__ dst,
                                                      int* __restrict__ cursor,
                                                      int* __restrict__ eidx) {
  int i = blockIdx.x * 256 + threadIdx.x;
  if (i < NEDGES) {
    int pos = atomicAdd(&cursor[dst[i]], 1);
    eidx[pos] = i;
  }
}

// ---------------- aggregation: one wave per node, bf16 edge rows ----------------
__global__ __launch_bounds__(256) void agg_kernel(const ushort* __restrict__ ebf,
                                                  ushort* __restrict__ abf,
                                                  const int* __restrict__ row_start,
                                                  const int* __restrict__ eidx) {
  int wv = threadIdx.x >> 6, lane = threadIdx.x & 63;
  int node = blockIdx.x * 4 + wv;
  if (node >= NNODES) return;
  int jb = row_start[node], je = row_start[node + 1];
  float ax = 0.f, ay = 0.f, bx = 0.f, by = 0.f;
  float cx = 0.f, cy = 0.f, dx = 0.f, dy = 0.f;
  int j = jb;
  for (; j + 3 < je; j += 4) {
    int e0 = eidx[j], e1 = eidx[j + 1], e2 = eidx[j + 2], e3 = eidx[j + 3];
    uint u0 = *(const uint*)(ebf + (size_t)e0 * DD + lane * 2);
    uint u1 = *(const uint*)(ebf + (size_t)e1 * DD + lane * 2);
    uint u2 = *(const uint*)(ebf + (size_t)e2 * DD + lane * 2);
    uint u3 = *(const uint*)(ebf + (size_t)e3 * DD + lane * 2);
    ax += bf2f((ushort)u0); ay += __builtin_bit_cast(float, u0 & 0xFFFF0000u);
    bx += bf2f((ushort)u1); by += __builtin_bit_cast(float, u1 & 0xFFFF0000u);
    cx += bf2f((ushort)u2); cy += __builtin_bit_cast(float, u2 & 0xFFFF0000u);
    dx += bf2f((ushort)u3); dy += __builtin_bit_cast(float, u3 & 0xFFFF0000u);
  }
  for (; j < je; ++j) {
    int e0 = eidx[j];
    uint u0 = *(const uint*)(ebf + (size_t)e0 * DD + lane * 2);
    ax += bf2f((ushort)u0); ay += __builtin_bit_cast(float, u0 & 0xFFFF0000u);
  }
  float sx = (ax + bx) + (cx + dx);
  float sy = (ay + by) + (cy + dy);
  ushort2 h;
  h.x = f2bf(sx); h.y = f2bf(sy);
  *(ushort2*)&abf[(size_t)node * DD + lane * 2] = h;
}

// ---------------- edge kernel: 32 edges x 128 out, 4 waves, bf16 residual ----------------
// LDS 32.8 KB -> 4 blocks/CU. GEMM2 output parked in dead src/dst region of Alds.
__global__ __launch_bounds__(256) void edge_kernel(
    const ushort* __restrict__ nbf, ushort* __restrict__ ebf,
    const int* __restrict__ srcI, const int* __restrict__ dstI,
    const ushort* __restrict__ w0, const float* __restrict__ b0,
    const ushort* __restrict__ w1, const float* __restrict__ b1,
    const ushort* __restrict__ w2, const float* __restrict__ b2) {
  __shared__ ushort Alds[32 * 384];   // cat tile (swizzled); chunks 0..15 reused as H2
  __shared__ ushort Hlds[32 * 128];   // hidden tile h1; reused as output bounce
  const int tid = threadIdx.x;
  const int e0 = blockIdx.x * 32;
  const int lane = tid & 63, wv = tid >> 6;
  const int l15 = lane & 15, l4 = lane >> 4;

  // stage cat = [n[src] | n[dst] | e] (bf16), 6 chunks of 16B per thread
#pragma unroll
  for (int i = 0; i < 6; ++i) {
    int c = i * 256 + tid;          // 0..1535
    int row = c / 48, f8 = c % 48;
    const ushort* sp;
    if (f8 < 16)       sp = nbf + (size_t)srcI[e0 + row] * DD + f8 * 8;
    else if (f8 < 32)  sp = nbf + (size_t)dstI[e0 + row] * DD + (f8 - 16) * 8;
    else               sp = ebf + (size_t)(e0 + row) * DD + (f8 - 32) * 8;
    bf16x8 v = *(const bf16x8*)sp;
    *(bf16x8*)&Alds[row * 384 + ((f8 ^ (row & 15)) * 8)] = v;
  }
  __syncthreads();

  const f32x4 z = {0.f, 0.f, 0.f, 0.f};
  const int cbA = wv * 2, cbB = wv * 2 + 1;
  f32x4 acc[2][2];

  // ---- GEMM1: [32x384] @ w0 ----
#pragma unroll
  for (int rb = 0; rb < 2; ++rb) { acc[rb][0] = z; acc[rb][1] = z; }
#pragma unroll
  for (int kt = 0; kt < 12; ++kt) {
    bf16x8 bA = *(const bf16x8*)(w0 + (size_t)((cbA * 12 + kt) * 64 + lane) * 8);
    bf16x8 bB = *(const bf16x8*)(w0 + (size_t)((cbB * 12 + kt) * 64 + lane) * 8);
#pragma unroll
    for (int rb = 0; rb < 2; ++rb) {
      int row = rb * 16 + l15;
      bf16x8 a = *(const bf16x8*)&Alds[row * 384 + (((kt * 4 + l4) ^ (row & 15)) * 8)];
      acc[rb][0] = mfma16(a, bA, acc[rb][0]);
      acc[rb][1] = mfma16(a, bB, acc[rb][1]);
    }
  }
  // ep1: h1 = relu(acc+b0) -> Hlds
  {
    float biasA = b0[cbA * 16 + l15], biasB = b0[cbB * 16 + l15];
#pragma unroll
    for (int cbi = 0; cbi < 2; ++cbi) {
      int col = (wv * 2 + cbi) * 16 + l15;
      float bias = cbi ? biasB : biasA;
#pragma unroll
      for (int rb = 0; rb < 2; ++rb)
#pragma unroll
        for (int r = 0; r < 4; ++r) {
          int row = rb * 16 + l4 * 4 + r;
          float v = fmaxf(acc[rb][cbi][r] + bias, 0.f);
          Hlds[row * 128 + (((col >> 3) ^ (row & 15)) * 8) + (col & 7)] = f2bf(v);
        }
    }
  }
  __syncthreads();

  // ---- GEMM2: h1 @ w1 ----
#pragma unroll
  for (int rb = 0; rb < 2; ++rb) { acc[rb][0] = z; acc[rb][1] = z; }
#pragma unroll
  for (int kt = 0; kt < 4; ++kt) {
    bf16x8 bA = *(const bf16x8*)(w1 + (size_t)((cbA * 4 + kt) * 64 + lane) * 8);
    bf16x8 bB = *(const bf16x8*)(w1 + (size_t)((cbB * 4 + kt) * 64 + lane) * 8);
#pragma unroll
    for (int rb = 0; rb < 2; ++rb) {
      int row = rb * 16 + l15;
      bf16x8 a = *(const bf16x8*)&Hlds[row * 128 + (((kt * 4 + l4) ^ (row & 15)) * 8)];
      acc[rb][0] = mfma16(a, bA, acc[rb][0]);
      acc[rb][1] = mfma16(a, bB, acc[rb][1]);
    }
  }
  // ep2: h2 = relu(acc+b1) -> Alds chunks 0..15 (src region, dead after GEMM1)
  {
    float biasA = b1[cbA * 16 + l15], biasB = b1[cbB * 16 + l15];
#pragma unroll
    for (int cbi = 0; cbi < 2; ++cbi) {
      int col = (wv * 2 + cbi) * 16 + l15;
      float bias = cbi ? biasB : biasA;
#pragma unroll
      for (int rb = 0; rb < 2; ++rb)
#pragma unroll
        for (int r = 0; r < 4; ++r) {
          int row = rb * 16 + l4 * 4 + r;
          float v = fmaxf(acc[rb][cbi][r] + bias, 0.f);
          Alds[row * 384 + (((col >> 3) ^ (row & 15)) * 8) + (col & 7)] = f2bf(v);
        }
    }
  }
  __syncthreads();

  // ---- GEMM3: h2 @ w2 (A from Alds chunks 0..15) ----
#pragma unroll
  for (int rb = 0; rb < 2; ++rb) { acc[rb][0] = z; acc[rb][1] = z; }
#pragma unroll
  for (int kt = 0; kt < 4; ++kt) {
    bf16x8 bA = *(const bf16x8*)(w2 + (size_t)((cbA * 4 + kt) * 64 + lane) * 8);
    bf16x8 bB = *(const bf16x8*)(w2 + (size_t)((cbB * 4 + kt) * 64 + lane) * 8);
#pragma unroll
    for (int rb = 0; rb < 2; ++rb) {
      int row = rb * 16 + l15;
      bf16x8 a = *(const bf16x8*)&Alds[row * 384 + (((kt * 4 + l4) ^ (row & 15)) * 8)];
      acc[rb][0] = mfma16(a, bA, acc[rb][0]);
      acc[rb][1] = mfma16(a, bB, acc[rb][1]);
    }
  }
  // final: res = e_in (Alds chunks 32..47) + acc + b2 -> Hlds (bf16), then coalesced out
  {
#pragma unroll
    for (int cbi = 0; cbi < 2; ++cbi) {
      int col = (wv * 2 + cbi) * 16 + l15;
      float bias = b2[col];
#pragma unroll
      for (int rb = 0; rb < 2; ++rb)
#pragma unroll
        for (int r = 0; r < 4; ++r) {
          int row = rb * 16 + l4 * 4 + r;
          float ein = bf2f(Alds[row * 384 + ((32 + ((col >> 3) ^ (row & 15))) * 8) + (col & 7)]);
          float res = ein + acc[rb][cbi][r] + bias;
          Hlds[row * 128 + (((col >> 3) ^ (row & 15)) * 8) + (col & 7)] = f2bf(res);
        }
    }
  }
  __syncthreads();
  // coalesced write-out: 2 x 16B chunks per thread
#pragma unroll
  for (int i = 0; i < 2; ++i) {
    int c = i * 256 + tid;          // 0..511
    int row = c >> 4, f8 = c & 15;
    bf16x8 v = *(const bf16x8*)&Hlds[row * 128 + ((f8 ^ (row & 15)) * 8)];
    *(bf16x8*)&ebf[(size_t)(e0 + row) * DD + f8 * 8] = v;
  }
}

// ---------------- node kernel: 32 nodes x 128 out, 4 waves, fp32 residual ----------------
__global__ __launch_bounds__(256) void node_kernel(
    float* __restrict__ nbuf, ushort* __restrict__ nbf,
    const ushort* __restrict__ abf,
    const ushort* __restrict__ w0, const float* __restrict__ b0,
    const ushort* __restrict__ w1, const float* __restrict__ b1,
    const ushort* __restrict__ w2, const float* __restrict__ b2) {
  __shared__ ushort Alds[32 * 256];   // [n | agg]; chunks 16..31 reused as H2
  __shared__ ushort Hlds[32 * 128];
  const int tid = threadIdx.x;
  const int n0 = blockIdx.x * 32;
  const int lane = tid & 63, wv = tid >> 6;
  const int l15 = lane & 15, l4 = lane >> 4;

  // stage cat_n = [n | agg] (bf16), 4 chunks per thread
#pragma unroll
  for (int i = 0; i < 4; ++i) {
    int c = i * 256 + tid;          // 0..1023
    int row = c >> 5, f8 = c & 31;
    int node = n0 + row;
    bf16x8 v = {0, 0, 0, 0, 0, 0, 0, 0};
    if (node < NNODES) {
      const ushort* sp = (f8 < 16) ? nbf + (size_t)node * DD + f8 * 8
                                   : abf + (size_t)node * DD + (f8 - 16) * 8;
      v = *(const bf16x8*)sp;
    }
    *(bf16x8*)&Alds[row * 256 + ((f8 ^ (row & 15)) * 8)] = v;
  }
  __syncthreads();

  const f32x4 z = {0.f, 0.f, 0.f, 0.f};
  const int cbA = wv * 2, cbB = wv * 2 + 1;
  f32x4 acc[2][2];

  // ---- GEMM1: [32x256] @ nw0 ----
#pragma unroll
  for (int rb = 0; rb < 2; ++rb) { acc[rb][0] = z; acc[rb][1] = z; }
#pragma unroll
  for (int kt = 0; kt < 8; ++kt) {
    bf16x8 bA = *(const bf16x8*)(w0 + (size_t)((cbA * 8 + kt) * 64 + lane) * 8);
    bf16x8 bB = *(const bf16x8*)(w0 + (size_t)((cbB * 8 + kt) * 64 + lane) * 8);
#pragma unroll
    for (int rb = 0; rb < 2; ++rb) {
      int row = rb * 16 + l15;
      bf16x8 a = *(const bf16x8*)&Alds[row * 256 + (((kt * 4 + l4) ^ (row & 15)) * 8)];
      acc[rb][0] = mfma16(a, bA, acc[rb][0]);
      acc[rb][1] = mfma16(a, bB, acc[rb][1]);
    }
  }
  {
    float biasA = b0[cbA * 16 + l15], biasB = b0[cbB * 16 + l15];
#pragma unroll
    for (int cbi = 0; cbi < 2; ++cbi) {
      int col = (wv * 2 + cbi) * 16 + l15;
      float bias = cbi ? biasB : biasA;
#pragma unroll
      for (int rb = 0; rb < 2; ++rb)
#pragma unroll
        for (int r = 0; r < 4; ++r) {
          int row = rb * 16 + l4 * 4 + r;
          float v = fmaxf(acc[rb][cbi][r] + bias, 0.f);
          Hlds[row * 128 + (((col >> 3) ^ (row & 15)) * 8) + (col & 7)] = f2bf(v);
        }
    }
  }
  __syncthreads();

  // ---- GEMM2 ----
#pragma unroll
  for (int rb = 0; rb < 2; ++rb) { acc[rb][0] = z; acc[rb][1] = z; }
#pragma unroll
  for (int kt = 0; kt < 4; ++kt) {
    bf16x8 bA = *(const bf16x8*)(w1 + (size_t)((cbA * 4 + kt) * 64 + lane) * 8);
    bf16x8 bB = *(const bf16x8*)(w1 + (size_t)((cbB * 4 + kt) * 64 + lane) * 8);
#pragma unroll
    for (int rb = 0; rb < 2; ++rb) {
      int row = rb * 16 + l15;
      bf16x8 a = *(const bf16x8*)&Hlds[row * 128 + (((kt * 4 + l4) ^ (row & 15)) * 8)];
      acc[rb][0] = mfma16(a, bA, acc[rb][0]);
      acc[rb][1] = mfma16(a, bB, acc[rb][1]);
    }
  }
  // ep2 -> Alds chunks 16..31 (agg region, dead after GEMM1)
  {
    float biasA = b1[cbA * 16 + l15], biasB = b1[cbB * 16 + l15];
#pragma unroll
    for (int cbi = 0; cbi < 2; ++cbi) {
      int col = (wv * 2 + cbi) * 16 + l15;
      float bias = cbi ? biasB : biasA;
#pragma unroll
      for (int rb = 0; rb < 2; ++rb)
#pragma unroll
        for (int r = 0; r < 4; ++r) {
          int row = rb * 16 + l4 * 4 + r;
          float v = fmaxf(acc[rb][cbi][r] + bias, 0.f);
          Alds[row * 256 + ((16 + ((col >> 3) ^ (row & 15))) * 8) + (col & 7)] = f2bf(v);
        }
    }
  }
  __syncthreads();

  // ---- GEMM3 + fp32 residual ----
#pragma unroll
  for (int rb = 0; rb < 2; ++rb) { acc[rb][0] = z; acc[rb][1] = z; }
#pragma unroll
  for (int kt = 0; kt < 4; ++kt) {
    bf16x8 bA = *(const bf16x8*)(w2 + (size_t)((cbA * 4 + kt) * 64 + lane) * 8);
    bf16x8 bB = *(const bf16x8*)(w2 + (size_t)((cbB * 4 + kt) * 64 + lane) * 8);
#pragma unroll
    for (int rb = 0; rb < 2; ++rb) {
      int row = rb * 16 + l15;
      bf16x8 a = *(const bf16x8*)&Alds[row * 256 + ((16 + ((kt * 4 + l4) ^ (row & 15))) * 8)];
      acc[rb][0] = mfma16(a, bA, acc[rb][0]);
      acc[rb][1] = mfma16(a, bB, acc[rb][1]);
    }
  }
  {
#pragma unroll
    for (int cbi = 0; cbi < 2; ++cbi) {
      int col = (wv * 2 + cbi) * 16 + l15;
      float bias = b2[col];
#pragma unroll
      for (int rb = 0; rb < 2; ++rb)
#pragma unroll
        for (int r = 0; r < 4; ++r) {
          int row = rb * 16 + l4 * 4 + r;
          int node = n0 + row;
          if (node < NNODES) {
            size_t off = (size_t)node * DD + col;
            float res = nbuf[off] + acc[rb][cbi][r] + bias;
            nbuf[off] = res;
            nbf[off] = f2bf(res);
          }
        }
    }
  }
}

extern "C" void kernel_launch(void* const* d_in, const int* in_sizes, int n_in,
                              void* d_out, int out_size, void* d_ws, size_t ws_size,
                              hipStream_t stream) {
  const float* node_f = (const float*)d_in[0];
  const float* edge_f = (const float*)d_in[1];
  const int* srcI = (const int*)d_in[2];
  const int* dstI = (const int*)d_in[3];
  const float* ew0 = (const float*)d_in[4];
  const float* eb0 = (const float*)d_in[5];
  const float* ew1 = (const float*)d_in[6];
  const float* eb1 = (const float*)d_in[7];
  const float* ew2 = (const float*)d_in[8];
  const float* eb2 = (const float*)d_in[9];
  const float* nw0 = (const float*)d_in[10];
  const float* nb0 = (const float*)d_in[11];
  const float* nw1 = (const float*)d_in[12];
  const float* nb1 = (const float*)d_in[13];
  const float* nw2 = (const float*)d_in[14];
  const float* nb2 = (const float*)d_in[15];

  char* ws = (char*)d_ws;
  const size_t NB  = (size_t)NNODES * DD * 4;   //  5,120,000
  const size_t EBH = (size_t)NEDGES * DD * 2;   // 40,960,000
  const size_t NBH = (size_t)NNODES * DD * 2;   //  2,560,000
  ushort* ebf  = (ushort*)ws;
  float*  nbuf = (float*)(ws + EBH);
  ushort* nbf  = (ushort*)(ws + EBH + NB);
  ushort* abf  = (ushort*)(ws + EBH + NB + NBH);
  ushort* pw   = (ushort*)(ws + EBH + NB + 2 * NBH);
  ushort* pew0 = pw;                    // 15*384*128
  ushort* pew1 = pew0 + 737280;         // 15*128*128
  ushort* pew2 = pew1 + 245760;
  ushort* pnw0 = pew2 + 245760;         // 15*256*128
  ushort* pnw1 = pnw0 + 491520;
  ushort* pnw2 = pnw1 + 245760;
  const size_t WBYTES = 2211840ull * 2;  // total packed-weight bytes
  int* eidx      = (int*)(ws + EBH + NB + 2 * NBH + WBYTES);
  int* cnt       = eidx + NEDGES;
  int* row_start = cnt + NNODES;
  int* cursor    = row_start + NNODES + 1;

  // pack all weights to bf16 fragment layout
  {
    struct { const float* s; ushort* d; int K; } packs[6] = {
      {ew0, pew0, 384}, {ew1, pew1, 128}, {ew2, pew2, 128},
      {nw0, pnw0, 256}, {nw1, pnw1, 128}, {nw2, pnw2, 128},
    };
    for (int i = 0; i < 6; ++i) {
      int total = PP * packs[i].K * 128;
      pack_w<<<(total + 255) / 256, 256, 0, stream>>>(packs[i].s, packs[i].d,
                                                      packs[i].K, total);
    }
  }

  // CSR build (graph is static across layers)
  hipMemsetAsync(cnt, 0, NNODES * sizeof(int), stream);
  hist_kernel<<<(NEDGES + 255) / 256, 256, 0, stream>>>(dstI, cnt);
  scan_kernel<<<1, 256, 0, stream>>>(cnt, row_start, cursor);
  scatter_kernel<<<(NEDGES + 255) / 256, 256, 0, stream>>>(dstI, cursor, eidx);

  // init streams
  {
    int en4 = NEDGES * DD / 4, nn4 = NNODES * DD / 4;
    cvt_bf<<<(en4 + 255) / 256, 256, 0, stream>>>(edge_f, ebf, en4);
    cvt_init<<<(nn4 + 255) / 256, 256, 0, stream>>>(node_f, nbuf, nbf, nn4);
  }

  const int eblocks = NEDGES / 32;                 // 5000
  const int nblocks = (NNODES + 31) / 32;          // 313
  const int ablocks = (NNODES + 3) / 4;            // 2500

  for (int p = 0; p < PP; ++p) {
    edge_kernel<<<eblocks, 256, 0, stream>>>(
        nbf, ebf, srcI, dstI,
        pew0 + (size_t)p * 49152, eb0 + (size_t)p * DD,
        pew1 + (size_t)p * 16384, eb1 + (size_t)p * DD,
        pew2 + (size_t)p * 16384, eb2 + (size_t)p * DD);
    agg_kernel<<<ablocks, 256, 0, stream>>>(ebf, abf, row_start, eidx);
    node_kernel<<<nblocks, 256, 0, stream>>>(
        nbuf, nbf, abf,
        pnw0 + (size_t)p * 32768, nb0 + (size_t)p * DD,
        pnw1 + (size_t)p * 16384, nb1 + (size_t)p * DD,
        pnw2 + (size_t)p * 16384, nb2 + (size_t)p * DD);
  }

  hipMemcpyAsync(d_out, nbuf, NB, hipMemcpyDeviceToDevice, stream);
}